// Round 4
// baseline (419.108 us; speedup 1.0000x reference)
//
#include <hip/hip_runtime.h>
#include <hip/hip_fp16.h>

#define DD 128            // emb dim, fixed by problem
#define SCAN_CHUNK 1024   // elements per scan1 block
#define ROWS_PER_BLK 16   // rows per gather block (16 lanes/row * 16 rows = 256)
#define MAX_STAGE 512     // staged edges per gather block (mean 256, +16 sigma)
#define NCOPY 8           // privatized histogram copies (one per XCD)

typedef float          f32x4 __attribute__((ext_vector_type(4)));
typedef unsigned int   u32x4 __attribute__((ext_vector_type(4)));
typedef unsigned int   u32x2 __attribute__((ext_vector_type(2)));
typedef unsigned short u16x8 __attribute__((ext_vector_type(8)));

struct __align__(8) Edge { int c; float v; };

// ---- fp16 helpers ----
__device__ __forceinline__ unsigned short f2h(float f) {
    return __half_as_ushort(__float2half(f));
}
__device__ __forceinline__ float2 up2(unsigned int u) {
    __half2 h = *reinterpret_cast<const __half2*>(&u);
    return __half22float2(h);
}

// ---- non-temporal access helpers (keep L2/L3 for the gather working set) ----
template <typename T>
__device__ __forceinline__ T ldnt(const T* p) { return __builtin_nontemporal_load(p); }
template <typename T>
__device__ __forceinline__ void stnt(T* p, T v) { __builtin_nontemporal_store(v, p); }

// ---- K1: g1 = fp16(dropout(emb,u1)) stream + per-thread hist edge ----------
// Privatized hist: copy k = blockIdx&7 -> with round-robin block->XCD dispatch
// each 400KB copy stays in ONE XCD's L2, so the returning atomic resolves
// locally. rank = (k<<13) | rank_within_copy  (ushort).
__global__ __launch_bounds__(256) void k_g1hist(const float* __restrict__ emb,
                                                const float* __restrict__ u1,
                                                ushort* __restrict__ g1,
                                                const int* __restrict__ rows,
                                                int* __restrict__ cnt8,
                                                ushort* __restrict__ rank,
                                                int total8, int E, int N) {
    int i = blockIdx.x * 256 + threadIdx.x;
    bool doE = i < E;
    bool doS = i < total8;
    int r = 0;
    if (doE) r = ldnt(rows + i);            // issue first: heads the atomic chain
    f32x4 hA, hB, uA, uB;
    if (doS) {                              // stream loads in flight under atomic
        const f32x4* e4 = (const f32x4*)emb;
        const f32x4* a4 = (const f32x4*)u1;
        hA = ldnt(e4 + 2 * (size_t)i);
        hB = ldnt(e4 + 2 * (size_t)i + 1);
        uA = ldnt(a4 + 2 * (size_t)i);
        uB = ldnt(a4 + 2 * (size_t)i + 1);
    }
    if (doE) {
        int k = blockIdx.x & (NCOPY - 1);
        int old = atomicAdd(&cnt8[(size_t)k * N + r], 1);
        stnt(rank + i, (ushort)((k << 13) | old));
    }
    if (doS) {
        const float s = 1.0f / 0.9f;
        u16x8 g;
        g[0] = f2h((uA.x >= 0.1f) ? hA.x * s : 0.0f);
        g[1] = f2h((uA.y >= 0.1f) ? hA.y * s : 0.0f);
        g[2] = f2h((uA.z >= 0.1f) ? hA.z * s : 0.0f);
        g[3] = f2h((uA.w >= 0.1f) ? hA.w * s : 0.0f);
        g[4] = f2h((uB.x >= 0.1f) ? hB.x * s : 0.0f);
        g[5] = f2h((uB.y >= 0.1f) ? hB.y * s : 0.0f);
        g[6] = f2h((uB.z >= 0.1f) ? hB.z * s : 0.0f);
        g[7] = f2h((uB.w >= 0.1f) ? hB.w * s : 0.0f);
        ((u16x8*)g1)[i] = g;   // normal store: gather1's working set
    }
}

// scan1: per row, fold the NCOPY histogram copies into within-row copy-offsets
// (written back in place) + row total; block-scan totals -> rs (exclusive),
// block totals -> bsum.
__global__ __launch_bounds__(256) void k_scan1(int* __restrict__ cnt8,
                                               int* __restrict__ rs,
                                               int* __restrict__ bsum, int n) {
    __shared__ int s[256];
    int tid = threadIdx.x;
    int base = blockIdx.x * SCAN_CHUNK + tid * 4;
    int tot[4];
#pragma unroll
    for (int j = 0; j < 4; ++j) {
        int row = base + j;
        int t = 0;
        if (row < n) {
            int c[NCOPY];
#pragma unroll
            for (int k = 0; k < NCOPY; ++k) c[k] = cnt8[(size_t)k * n + row];
#pragma unroll
            for (int k = 0; k < NCOPY; ++k) {
                int cc = c[k];
                cnt8[(size_t)k * n + row] = t;   // within-row copy offset
                t += cc;
            }
        }
        tot[j] = t;
    }
    int tsum = tot[0] + tot[1] + tot[2] + tot[3];
    s[tid] = tsum;
    __syncthreads();
    for (int off = 1; off < 256; off <<= 1) {
        int t = (tid >= off) ? s[tid - off] : 0;
        __syncthreads();
        s[tid] += t;
        __syncthreads();
    }
    int excl = s[tid] - tsum;
    if (tid == 255) bsum[blockIdx.x] = s[255];
    int run = excl;
#pragma unroll
    for (int j = 0; j < 4; ++j) {
        int row = base + j;
        if (row < n) rs[row] = run;
        run += tot[j];
    }
}

// fused scan2+scan3: serial prefix of bsum (nb<=1024) in LDS, add block offset.
// rs becomes the global rowstart.
__global__ __launch_bounds__(256) void k_scan23(int* __restrict__ rs,
                                                const int* __restrict__ bsum,
                                                int nb, int n) {
    __shared__ int s[1024];
    int tid = threadIdx.x;
    for (int i = tid; i < nb; i += 256) s[i] = bsum[i];
    __syncthreads();
    if (tid == 0) {
        int run = 0;
        for (int i = 0; i < nb; ++i) { int t = s[i]; s[i] = run; run += t; }
    }
    __syncthreads();
    int i = blockIdx.x * 256 + tid;
    if (i < n) rs[i] += s[i >> 10];
}

// ---- K4: rank-based edge scatter + emb16/mask2 stream ----------------------
// pos = rs[r] + copyoff(cnt8[k][r]) + rank_in_copy  (no atomic). Latency of
// the random lookups/store hides under the emb16/mask2 streaming bandwidth.
__global__ __launch_bounds__(256) void k_scatter_prep(const int* __restrict__ rows,
                                                      const int* __restrict__ cols,
                                                      const float* __restrict__ vals,
                                                      const int* __restrict__ rs,
                                                      const int* __restrict__ cnt8,
                                                      const ushort* __restrict__ rank,
                                                      Edge* __restrict__ ev,
                                                      const float* __restrict__ emb,
                                                      const float* __restrict__ u2,
                                                      ushort* __restrict__ emb16,
                                                      unsigned char* __restrict__ mask2,
                                                      int E, int total8, int N) {
    int i = blockIdx.x * 256 + threadIdx.x;
    bool doE = i < E;
    bool doS = i < total8;
    int r = 0, c = 0; float v = 0.f; unsigned int rk = 0;
    if (doE) {
        r = ldnt(rows + i);
        c = ldnt(cols + i);
        v = ldnt(vals + i);
        rk = ldnt(rank + i);
    }
    f32x4 hA, hB, vA, vB;
    if (doS) {
        const f32x4* e4 = (const f32x4*)emb;
        const f32x4* b4 = (const f32x4*)u2;
        hA = ldnt(e4 + 2 * (size_t)i);
        hB = ldnt(e4 + 2 * (size_t)i + 1);
        vA = ldnt(b4 + 2 * (size_t)i);
        vB = ldnt(b4 + 2 * (size_t)i + 1);
    }
    if (doE) {
        int k = rk >> 13;
        int rin = rk & 0x1FFF;
        int pos = rs[r] + cnt8[(size_t)k * N + r] + rin;   // hot 0.4/3.2MB, L2
        u32x2 q;
        q.x = (unsigned int)c;
        q.y = __float_as_uint(v);
        ((u32x2*)ev)[pos] = q;        // normal store: L2/L3 absorbs amplification
    }
    if (doS) {
        u16x8 e16;
        e16[0] = f2h(hA.x); e16[1] = f2h(hA.y); e16[2] = f2h(hA.z); e16[3] = f2h(hA.w);
        e16[4] = f2h(hB.x); e16[5] = f2h(hB.y); e16[6] = f2h(hB.z); e16[7] = f2h(hB.w);
        stnt((u16x8*)emb16 + i, e16);
        unsigned char m =
            (unsigned char)((vA.x >= 0.1f ? 1u : 0u)  | (vA.y >= 0.1f ? 2u : 0u)  |
                            (vA.z >= 0.1f ? 4u : 0u)  | (vA.w >= 0.1f ? 8u : 0u)  |
                            (vB.x >= 0.1f ? 16u : 0u) | (vB.y >= 0.1f ? 32u : 0u) |
                            (vB.z >= 0.1f ? 64u : 0u) | (vB.w >= 0.1f ? 128u : 0u));
        stnt(mask2 + i, m);
    }
}

// ---- gather SpMM --------------------------------------------------------
// 16 rows/block, 16 lanes/row, 8 halves (16B) per lane. Block's CSR edge
// range is contiguous -> cooperative LDS stage (1 barrier), then each group
// reads edges from LDS (broadcast) and issues gathers 8-deep uninterrupted.
// MODE 1: p16 = fp16(h1 = A*src); g2 = fp16(dropout(h1) via mask2 bits)
// MODE 2: out = (emb16 + p16in + A*src) / 3   [fp32]
template <int MODE>
__global__ __launch_bounds__(256) void k_gather(const int* __restrict__ rowstart,
                                                const Edge* __restrict__ ev,
                                                const ushort* __restrict__ srch,
                                                const unsigned char* __restrict__ mask2,
                                                const ushort* __restrict__ emb16,
                                                const ushort* __restrict__ p16in,
                                                ushort* __restrict__ p16out,
                                                ushort* __restrict__ g2,
                                                float* __restrict__ out,
                                                int N, int E) {
    __shared__ int s_rs[ROWS_PER_BLK + 1];
    __shared__ Edge s_ev[MAX_STAGE];

    int tid = threadIdx.x;
    int r0 = blockIdx.x * ROWS_PER_BLK;
    if (tid <= ROWS_PER_BLK) {
        int r = r0 + tid;
        s_rs[tid] = (r < N) ? rowstart[r] : E;
    }
    __syncthreads();
    int base = s_rs[0];
    int nblk = s_rs[ROWS_PER_BLK] - base;
    int nstage = nblk < MAX_STAGE ? nblk : MAX_STAGE;
    for (int i = tid; i < nstage; i += 256) {
        u32x2 q = ldnt((const u32x2*)(ev + base + i));
        Edge ed; ed.c = (int)q.x; ed.v = __uint_as_float(q.y);
        s_ev[i] = ed;
    }
    __syncthreads();

    int grp = tid >> 4;
    int lane = tid & 15;
    int row = r0 + grp;
    if (row >= N) return;
    int start = s_rs[grp] - base;
    int end = s_rs[grp + 1] - base;
    int eL = end < nstage ? end : nstage;

    const u32x4* __restrict__ s4 = (const u32x4*)srch;  // 8 halves per u32x4
    const Edge* __restrict__ evg = ev + base;
    float a0 = 0.f, a1 = 0.f, a2 = 0.f, a3 = 0.f;
    float a4 = 0.f, a5 = 0.f, a6 = 0.f, a7 = 0.f;

#define LDE(i) Edge E##i = s_ev[e + i];
#define GQ(i)  u32x4 q##i = s4[((size_t)E##i.c << 4) + lane];
#define ACC(i) { float vv = E##i.v; \
        float2 w0 = up2(q##i.x), w1 = up2(q##i.y), w2 = up2(q##i.z), w3 = up2(q##i.w); \
        a0 = fmaf(vv, w0.x, a0); a1 = fmaf(vv, w0.y, a1); \
        a2 = fmaf(vv, w1.x, a2); a3 = fmaf(vv, w1.y, a3); \
        a4 = fmaf(vv, w2.x, a4); a5 = fmaf(vv, w2.y, a5); \
        a6 = fmaf(vv, w3.x, a6); a7 = fmaf(vv, w3.y, a7); }

    int e = start;
    for (; e + 8 <= eL; e += 8) {
        LDE(0) LDE(1) LDE(2) LDE(3) LDE(4) LDE(5) LDE(6) LDE(7)
        GQ(0) GQ(1) GQ(2) GQ(3) GQ(4) GQ(5) GQ(6) GQ(7)
        ACC(0) ACC(1) ACC(2) ACC(3) ACC(4) ACC(5) ACC(6) ACC(7)
    }
    if (e + 4 <= eL) {
        LDE(0) LDE(1) LDE(2) LDE(3)
        GQ(0) GQ(1) GQ(2) GQ(3)
        ACC(0) ACC(1) ACC(2) ACC(3)
        e += 4;
    }
    for (; e < eL; ++e) {
        LDE(0) GQ(0) ACC(0)
    }
    // rare spill: block had >MAX_STAGE edges; finish from global
    for (; e < end; ++e) {
        Edge E0; { u32x2 q_ = ldnt((const u32x2*)(evg + e));
                   E0.c = (int)q_.x; E0.v = __uint_as_float(q_.y); }
        GQ(0) ACC(0)
    }
#undef LDE
#undef GQ
#undef ACC

    size_t o = ((size_t)row << 7) + (size_t)lane * 8;
    if (MODE == 1) {
        unsigned int m = ldnt(mask2 + (size_t)row * 16 + lane);
        const float s = 1.0f / 0.9f;
        u16x8 gg;
        gg[0] = (m & 1u)   ? f2h(a0 * s) : (ushort)0;
        gg[1] = (m & 2u)   ? f2h(a1 * s) : (ushort)0;
        gg[2] = (m & 4u)   ? f2h(a2 * s) : (ushort)0;
        gg[3] = (m & 8u)   ? f2h(a3 * s) : (ushort)0;
        gg[4] = (m & 16u)  ? f2h(a4 * s) : (ushort)0;
        gg[5] = (m & 32u)  ? f2h(a5 * s) : (ushort)0;
        gg[6] = (m & 64u)  ? f2h(a6 * s) : (ushort)0;
        gg[7] = (m & 128u) ? f2h(a7 * s) : (ushort)0;
        stnt((u16x8*)(g2 + o), gg);
        u16x8 pp;
        pp[0] = f2h(a0); pp[1] = f2h(a1); pp[2] = f2h(a2); pp[3] = f2h(a3);
        pp[4] = f2h(a4); pp[5] = f2h(a5); pp[6] = f2h(a6); pp[7] = f2h(a7);
        stnt((u16x8*)(p16out + o), pp);
    } else {
        u32x4 eq = ldnt((const u32x4*)(emb16 + o));
        u32x4 pq = ldnt((const u32x4*)(p16in + o));
        float2 e0 = up2(eq.x), e1 = up2(eq.y), e2 = up2(eq.z), e3 = up2(eq.w);
        float2 p0 = up2(pq.x), p1 = up2(pq.y), p2 = up2(pq.z), p3 = up2(pq.w);
        const float t3 = 1.0f / 3.0f;
        f32x4 rA, rB;
        rA.x = (e0.x + p0.x + a0) * t3;
        rA.y = (e0.y + p0.y + a1) * t3;
        rA.z = (e1.x + p1.x + a2) * t3;
        rA.w = (e1.y + p1.y + a3) * t3;
        rB.x = (e2.x + p2.x + a4) * t3;
        rB.y = (e2.y + p2.y + a5) * t3;
        rB.z = (e3.x + p3.x + a6) * t3;
        rB.w = (e3.y + p3.y + a7) * t3;
        stnt((f32x4*)(out + o), rA);
        stnt((f32x4*)(out + o) + 1, rB);
    }
}

// ---- launch -------------------------------------------------------------

extern "C" void kernel_launch(void* const* d_in, const int* in_sizes, int n_in,
                              void* d_out, int out_size, void* d_ws, size_t ws_size,
                              hipStream_t stream) {
    const int* rows = (const int*)d_in[1];
    const int* cols = (const int*)d_in[2];
    const float* vals = (const float*)d_in[3];
    const float* emb = (const float*)d_in[4];
    const float* u1 = (const float*)d_in[5];
    const float* u2 = (const float*)d_in[6];
    float* out = (float*)d_out;

    const int N = in_sizes[0];
    const int E = in_sizes[1];
    const size_t ND = (size_t)N * DD;

    // workspace layout (~123.6 MB, same footprint as round 3)
    char* ws = (char*)d_ws;
    Edge* ev     = (Edge*)ws;   ws += (size_t)E * sizeof(Edge);        // 12.8MB
    ushort* g1   = (ushort*)ws; ws += ND * sizeof(ushort);             // 25.6MB fp16
    ushort* g2   = (ushort*)ws; ws += ND * sizeof(ushort);             // 25.6MB fp16
    ushort* p16  = (ushort*)ws; ws += ND * sizeof(ushort);             // 25.6MB fp16 h1
    ushort* emb16= (ushort*)ws; ws += ND * sizeof(ushort);             // 25.6MB fp16 emb
    int* cnt8    = (int*)ws;    ws += (size_t)NCOPY * N * sizeof(int); // 3.2MB
    int* rs      = (int*)ws;    ws += (size_t)N * sizeof(int);         // 0.4MB rowstart
    ushort* rank = (ushort*)ws; ws += (size_t)E * sizeof(ushort);      // 3.2MB
    int* bsum    = (int*)ws;    ws += 4096;
    unsigned char* mask2 = (unsigned char*)ws;                         // 1.6MB

    const int total8 = (int)(ND / 8);
    const int prepBlocks = (total8 + 255) / 256;
    const int gridE = (E + 255) / 256;
    const int gridFuse = prepBlocks > gridE ? prepBlocks : gridE;
    const int nScanBlocks = (N + SCAN_CHUNK - 1) / SCAN_CHUNK;
    const int gridRow = (N + ROWS_PER_BLK - 1) / ROWS_PER_BLK;

    hipMemsetAsync(cnt8, 0, (size_t)NCOPY * N * sizeof(int), stream);
    // g1 stream + privatized hist (thread-level fusion)
    k_g1hist<<<gridFuse, 256, 0, stream>>>(emb, u1, g1, rows, cnt8, rank,
                                           total8, E, N);
    k_scan1<<<nScanBlocks, 256, 0, stream>>>(cnt8, rs, bsum, N);
    k_scan23<<<(N + 255) / 256, 256, 0, stream>>>(rs, bsum, nScanBlocks, N);
    // rank-based scatter + emb16/mask2 stream (thread-level fusion)
    k_scatter_prep<<<gridFuse, 256, 0, stream>>>(rows, cols, vals, rs, cnt8, rank,
                                                 ev, emb, u2, emb16, mask2,
                                                 E, total8, N);
    // h1 = A*g1; p16 = fp16(h1); g2 = fp16(dropout(h1, mask2))
    k_gather<1><<<gridRow, 256, 0, stream>>>(rs, ev, g1, mask2, nullptr, nullptr,
                                             p16, g2, nullptr, N, E);
    // out = (emb16 + p16 + A*g2)/3
    k_gather<2><<<gridRow, 256, 0, stream>>>(rs, ev, g2, nullptr, emb16, p16,
                                             nullptr, nullptr, out, N, E);
}